// Round 1
// baseline (544.114 us; speedup 1.0000x reference)
//
#include <hip/hip_runtime.h>

// ---------------------------------------------------------------------------
// Downsampling_33311766347847 — fp32 correctness-first implementation.
// Pipeline (all linear):
//   stage1: frames[8128,1022] = A1[8128,1024] @ M1[1024,1022]   (irfft * SYNTH)
//   ola:    sig[64,33278]     = overlap-add of frames (<=4 terms per sample)
//   stage2: out = fr[3968,1022] @ M2[1022,1024]  (fr = gathered decimated sig,
//            Hann folded into M2 rows; rfft basis)
// All dims padded to 1024; row counts 8128=127*64, 3968=62*64 exact tiles.
// ---------------------------------------------------------------------------

#define WIN       1022
#define HOP       256
#define T_IN      127
#define NB        64
#define NPAD      1024
#define L_OLA     33278     // (127-1)*256 + 1022
#define T_OUT     62
#define HALF_KEPT 16608     // 33216/2
#define ROWS1     (NB * T_IN)    // 8128
#define ROWS2     (NB * T_OUT)   // 3968
#define TWO_PI_F  6.28318530717958647692f

// ------------------------------- table builders ----------------------------

__global__ void build_windows(float* __restrict__ synth, float* __restrict__ window) {
    int j = blockIdx.x * blockDim.x + threadIdx.x;
    if (j >= NPAD) return;
    if (j >= WIN) { synth[j] = 0.f; window[j] = 0.f; return; }
    const float c = TWO_PI_F / (float)WIN;
    float w = 0.5f - 0.5f * cosf(c * (float)j);
    int p = j & (HOP - 1);
    float dd = 0.f;
    for (int r = 0; r < 4; ++r) {
        int idx = p + HOP * r;
        if (idx < WIN) {
            float wi = 0.5f - 0.5f * cosf(c * (float)idx);
            dd += wi * wi;
        }
    }
    synth[j]  = w / dd;
    window[j] = w;
}

// M1[kk][j], kk = 2k+c over 1024 rows, j over 1024 cols (cols >=1022 zero).
// irfft: x[j] = (1/N)[ReX0 + (-1)^j ReX511 + 2*sum_{k=1}^{510}(Re cos - Im sin)]
__global__ void build_m1(float* __restrict__ M1, const float* __restrict__ synth) {
    int idx = blockIdx.x * blockDim.x + threadIdx.x;   // 1024*1024
    int kk = idx >> 10, j = idx & 1023;
    float v = 0.f;
    if (j < WIN) {
        int k = kk >> 1, c = kk & 1;
        if (!(c == 1 && (k == 0 || k == 511))) {       // Im of DC/Nyquist ignored
            float a = (k == 0 || k == 511) ? (1.f / (float)WIN) : (2.f / (float)WIN);
            int m = (k * j) % WIN;                     // exact phase reduction
            float ang = (float)m * (TWO_PI_F / (float)WIN);
            float s, co;
            __sincosf(ang, &s, &co);
            v = a * synth[j] * (c == 0 ? co : -s);
        }
    }
    M1[idx] = v;
}

// M2[j][col], col = 2k+c; rows j>=1022 zero; Hann folded into rows.
// rfft: S[k] = sum_j fr[j] (cos - i sin)(2*pi*k*j/N)
__global__ void build_m2(float* __restrict__ M2, const float* __restrict__ window) {
    int idx = blockIdx.x * blockDim.x + threadIdx.x;   // 1024*1024
    int j = idx >> 10, col = idx & 1023;
    float v = 0.f;
    if (j < WIN) {
        int k = col >> 1, c = col & 1;
        int m = (k * j) % WIN;
        float ang = (float)m * (TWO_PI_F / (float)WIN);
        float s, co;
        __sincosf(ang, &s, &co);
        v = window[j] * (c == 0 ? co : -s);
    }
    M2[idx] = v;
}

// A1[row=b*127+t][kk=2k+c] = in[((b*512+k)*127+t)*2+c]
__global__ void pack_a(const float* __restrict__ in, float* __restrict__ A1) {
    int row = blockIdx.x;
    int b = row / T_IN, t = row % T_IN;
    const float* src = in + ((size_t)b * 512 * T_IN + t) * 2;
    float* dst = A1 + (size_t)row * NPAD;
    for (int kk = threadIdx.x; kk < NPAD; kk += 256) {
        int k = kk >> 1, c = kk & 1;
        dst[kk] = src[(size_t)k * (T_IN * 2) + c];
    }
}

// ------------------------------- GEMMs -------------------------------------
// 64x64 tile, BK=16, 256 threads, 4x4 micro-tile per thread.

#define BM 64
#define BN 64
#define BK 16

__global__ __launch_bounds__(256) void gemm1(const float* __restrict__ A,
                                             const float* __restrict__ B,
                                             float* __restrict__ C) {
    __shared__ float As[BK][BM + 1];
    __shared__ float Bs[BK][BN];
    int tid = threadIdx.x;
    int rowBase = blockIdx.y * BM;
    int colBase = blockIdx.x * BN;
    int ty = tid >> 4, tx = tid & 15;
    int am = tid >> 2, ak = (tid & 3) * 4;
    int bk = tid >> 4, bn = (tid & 15) * 4;

    float acc[4][4] = {};
    for (int k0 = 0; k0 < NPAD; k0 += BK) {
        float4 av = *(const float4*)&A[(size_t)(rowBase + am) * NPAD + k0 + ak];
        As[ak + 0][am] = av.x;
        As[ak + 1][am] = av.y;
        As[ak + 2][am] = av.z;
        As[ak + 3][am] = av.w;
        float4 bv = *(const float4*)&B[(size_t)(k0 + bk) * NPAD + colBase + bn];
        *(float4*)&Bs[bk][bn] = bv;
        __syncthreads();
#pragma unroll
        for (int kk = 0; kk < BK; ++kk) {
            float a0 = As[kk][ty * 4 + 0];
            float a1 = As[kk][ty * 4 + 1];
            float a2 = As[kk][ty * 4 + 2];
            float a3 = As[kk][ty * 4 + 3];
            float4 b4 = *(const float4*)&Bs[kk][tx * 4];
            acc[0][0] += a0 * b4.x; acc[0][1] += a0 * b4.y; acc[0][2] += a0 * b4.z; acc[0][3] += a0 * b4.w;
            acc[1][0] += a1 * b4.x; acc[1][1] += a1 * b4.y; acc[1][2] += a1 * b4.z; acc[1][3] += a1 * b4.w;
            acc[2][0] += a2 * b4.x; acc[2][1] += a2 * b4.y; acc[2][2] += a2 * b4.z; acc[2][3] += a2 * b4.w;
            acc[3][0] += a3 * b4.x; acc[3][1] += a3 * b4.y; acc[3][2] += a3 * b4.z; acc[3][3] += a3 * b4.w;
        }
        __syncthreads();
    }
#pragma unroll
    for (int i = 0; i < 4; ++i) {
        float4 cv = make_float4(acc[i][0], acc[i][1], acc[i][2], acc[i][3]);
        *(float4*)&C[(size_t)(rowBase + ty * 4 + i) * NPAD + colBase + tx * 4] = cv;
    }
}

// sig[b][s] = sum over frames t covering s
__global__ void ola(const float* __restrict__ frames, float* __restrict__ sig) {
    int s = blockIdx.x * 256 + threadIdx.x;
    int b = blockIdx.y;
    if (s >= L_OLA) return;
    int tmin = (s - (WIN - 1) + (HOP - 1)) / HOP;  // ceil((s-1021)/256), clamped
    if (tmin < 0) tmin = 0;
    int tmax = s >> 8;
    if (tmax > T_IN - 1) tmax = T_IN - 1;
    float acc = 0.f;
    for (int t = tmin; t <= tmax; ++t)
        acc += frames[(size_t)(b * T_IN + t) * NPAD + (s - t * HOP)];
    sig[(size_t)b * L_OLA + s] = acc;
}

// keep(i): i<16608 -> 2i ; else i+16608
__device__ __forceinline__ float gather_fr(const float* __restrict__ sig,
                                           int b, int t2, int j) {
    if (j >= WIN) return 0.f;
    int i = t2 * HOP + j;
    int s = (i < HALF_KEPT) ? (2 * i) : (i + HALF_KEPT);
    return sig[(size_t)b * L_OLA + s];
}

__global__ __launch_bounds__(256) void gemm2(const float* __restrict__ sig,
                                             const float* __restrict__ B,
                                             float* __restrict__ out) {
    __shared__ float As[BK][BM + 1];
    __shared__ float Bs[BK][BN];
    int tid = threadIdx.x;
    int rowBase = blockIdx.y * BM;
    int colBase = blockIdx.x * BN;
    int ty = tid >> 4, tx = tid & 15;
    int am = tid >> 2, ak = (tid & 3) * 4;
    int bk = tid >> 4, bn = (tid & 15) * 4;

    int arow = rowBase + am;
    int ab = arow / T_OUT, at2 = arow % T_OUT;

    float acc[4][4] = {};
    for (int k0 = 0; k0 < NPAD; k0 += BK) {
#pragma unroll
        for (int i = 0; i < 4; ++i)
            As[ak + i][am] = gather_fr(sig, ab, at2, k0 + ak + i);
        float4 bv = *(const float4*)&B[(size_t)(k0 + bk) * NPAD + colBase + bn];
        *(float4*)&Bs[bk][bn] = bv;
        __syncthreads();
#pragma unroll
        for (int kk = 0; kk < BK; ++kk) {
            float a0 = As[kk][ty * 4 + 0];
            float a1 = As[kk][ty * 4 + 1];
            float a2 = As[kk][ty * 4 + 2];
            float a3 = As[kk][ty * 4 + 3];
            float4 b4 = *(const float4*)&Bs[kk][tx * 4];
            acc[0][0] += a0 * b4.x; acc[0][1] += a0 * b4.y; acc[0][2] += a0 * b4.z; acc[0][3] += a0 * b4.w;
            acc[1][0] += a1 * b4.x; acc[1][1] += a1 * b4.y; acc[1][2] += a1 * b4.z; acc[1][3] += a1 * b4.w;
            acc[2][0] += a2 * b4.x; acc[2][1] += a2 * b4.y; acc[2][2] += a2 * b4.z; acc[2][3] += a2 * b4.w;
            acc[3][0] += a3 * b4.x; acc[3][1] += a3 * b4.y; acc[3][2] += a3 * b4.z; acc[3][3] += a3 * b4.w;
        }
        __syncthreads();
    }
    // scatter store: row = b*62+t2, col = 2k+c -> out[((b*512+k)*62+t2)*2+c]
#pragma unroll
    for (int i = 0; i < 4; ++i) {
        int row = rowBase + ty * 4 + i;
        int b = row / T_OUT, t2 = row % T_OUT;
#pragma unroll
        for (int jj = 0; jj < 4; ++jj) {
            int col = colBase + tx * 4 + jj;
            int k = col >> 1, c = col & 1;
            out[(((size_t)b * 512 + k) * T_OUT + t2) * 2 + c] = acc[i][jj];
        }
    }
}

// ------------------------------- launcher ----------------------------------

extern "C" void kernel_launch(void* const* d_in, const int* in_sizes, int n_in,
                              void* d_out, int out_size, void* d_ws, size_t ws_size,
                              hipStream_t stream) {
    const float* in = (const float*)d_in[0];
    float* out = (float*)d_out;
    float* ws = (float*)d_ws;

    // workspace layout (floats)
    float* M1     = ws;                          // 1024*1024
    float* M2     = M1 + (size_t)NPAD * NPAD;    // 1024*1024
    float* A1     = M2 + (size_t)NPAD * NPAD;    // 8128*1024
    float* frames = A1 + (size_t)ROWS1 * NPAD;   // 8128*1024
    float* sig    = frames + (size_t)ROWS1 * NPAD; // 64*33278
    float* synth  = sig + (size_t)NB * L_OLA;    // 1024
    float* window = synth + NPAD;                // 1024

    build_windows<<<4, 256, 0, stream>>>(synth, window);
    build_m1<<<(NPAD * NPAD) / 256, 256, 0, stream>>>(M1, synth);
    build_m2<<<(NPAD * NPAD) / 256, 256, 0, stream>>>(M2, window);
    pack_a<<<ROWS1, 256, 0, stream>>>(in, A1);
    gemm1<<<dim3(NPAD / BN, ROWS1 / BM), 256, 0, stream>>>(A1, M1, frames);
    ola<<<dim3((L_OLA + 255) / 256, NB), 256, 0, stream>>>(frames, sig);
    gemm2<<<dim3(NPAD / BN, ROWS2 / BM), 256, 0, stream>>>(sig, M2, out);
}

// Round 2
// 195.150 us; speedup vs baseline: 2.7882x; 2.7882x over previous
//
#include <hip/hip_runtime.h>

// ---------------------------------------------------------------------------
// Downsampling — fp16 MFMA implementation (m97-style GEMM structure).
//   stage1: frames[8192,1024]f32 = A1[8192,1024]f16 @ M1T[1024,1024]f16^T
//   ola:    sig[64,33278]f32
//   pack_fr: fr[4096,1024]f16 (decimation gather + zero pad)
//   stage2: out = fr @ M2T^T, scatter-store into (b,512,62,2) layout
// M1T[n][k], M2T[n][k] built transposed so B-tiles stage contiguously via
// global_load_lds (wave-uniform base + lane*16 — no scatter allowed).
// ---------------------------------------------------------------------------

#define WIN       1022
#define HOP       256
#define T_IN      127
#define NB        64
#define NPAD      1024
#define L_OLA     33278     // (127-1)*256 + 1022
#define T_OUT     62
#define HALF_KEPT 16608     // 33216/2
#define ROWS1     (NB * T_IN)    // 8128
#define ROWS1P    8192
#define ROWS2     (NB * T_OUT)   // 3968
#define ROWS2P    4096
#define TWO_PI_F  6.28318530717958647692f

typedef _Float16 half8 __attribute__((ext_vector_type(8)));
typedef float    f32x4 __attribute__((ext_vector_type(4)));

// ------------------------------- table builders ----------------------------

__global__ void build_windows(float* __restrict__ synth, float* __restrict__ window) {
    int j = blockIdx.x * blockDim.x + threadIdx.x;
    if (j >= NPAD) return;
    if (j >= WIN) { synth[j] = 0.f; window[j] = 0.f; return; }
    const float c = TWO_PI_F / (float)WIN;
    float w = 0.5f - 0.5f * cosf(c * (float)j);
    int p = j & (HOP - 1);
    float dd = 0.f;
    for (int r = 0; r < 4; ++r) {
        int idx = p + HOP * r;
        if (idx < WIN) {
            float wi = 0.5f - 0.5f * cosf(c * (float)idx);
            dd += wi * wi;
        }
    }
    synth[j]  = w / dd;
    window[j] = w;
}

// M1T[j][kk] = irfft basis * synth, kk = 2k+c.  (transposed vs math layout)
__global__ void build_m1t(_Float16* __restrict__ M1T, const float* __restrict__ synth) {
    int idx = blockIdx.x * blockDim.x + threadIdx.x;   // 1024*1024
    int j = idx >> 10, kk = idx & 1023;
    float v = 0.f;
    if (j < WIN) {
        int k = kk >> 1, c = kk & 1;
        if (!(c == 1 && (k == 0 || k == 511))) {       // Im of DC/Nyquist ignored
            float a = (k == 0 || k == 511) ? (1.f / (float)WIN) : (2.f / (float)WIN);
            int m = (k * j) % WIN;                     // exact phase reduction
            float ang = (float)m * (TWO_PI_F / (float)WIN);
            float s, co;
            sincosf(ang, &s, &co);
            v = a * synth[j] * (c == 0 ? co : -s);
        }
    }
    M1T[idx] = (_Float16)v;
}

// M2T[col][j] = rfft basis * hann, col = 2k+c.  (transposed: row=output col)
__global__ void build_m2t(_Float16* __restrict__ M2T, const float* __restrict__ window) {
    int idx = blockIdx.x * blockDim.x + threadIdx.x;   // 1024*1024
    int col = idx >> 10, j = idx & 1023;
    float v = 0.f;
    if (j < WIN) {
        int k = col >> 1, c = col & 1;
        int m = (k * j) % WIN;
        float ang = (float)m * (TWO_PI_F / (float)WIN);
        float s, co;
        sincosf(ang, &s, &co);
        v = window[j] * (c == 0 ? co : -s);
    }
    M2T[idx] = (_Float16)v;
}

// A1[row=b*127+t][kk=2k+c] = in[((b*512+k)*127+t)*2+c], fp16; rows>=8128 zero
__global__ void pack_a(const float* __restrict__ in, _Float16* __restrict__ A1) {
    int row = blockIdx.x;
    _Float16* dst = A1 + (size_t)row * NPAD;
    if (row >= ROWS1) {
        for (int kk = threadIdx.x; kk < NPAD; kk += 256) dst[kk] = (_Float16)0.f;
        return;
    }
    int b = row / T_IN, t = row % T_IN;
    const float* src = in + ((size_t)b * 512 * T_IN + t) * 2;
    for (int kk = threadIdx.x; kk < NPAD; kk += 256) {
        int k = kk >> 1, c = kk & 1;
        dst[kk] = (_Float16)src[(size_t)k * (T_IN * 2) + c];
    }
}

// ------------------------------- MFMA GEMM ---------------------------------
// C[128x128] per block; 4 waves in 2x2; per wave 4x4 tiles of 16x16.
// LDS: As[128][32] f16, Bs[128][32] f16 (B stored transposed: row=n, col=k).

__device__ __forceinline__ void stage16(const void* g, void* l) {
    __builtin_amdgcn_global_load_lds(
        (const __attribute__((address_space(1))) unsigned int*)g,
        (__attribute__((address_space(3))) unsigned int*)l, 16, 0, 0);
}

// Stage a [128 rows x 32 halves] tile from row-major [*,1024] f16 matrix.
// LDS layout row-major [128][32]; thread t handles 16B: row t/4, half-off (t%4)*8.
__device__ __forceinline__ void stage_tile(const _Float16* __restrict__ G,
                                           int row0, int k0,
                                           _Float16* __restrict__ L, int tid) {
    int r = tid >> 2, ko = (tid & 3) * 8;
    stage16(G + (size_t)(row0 + r) * NPAD + k0 + ko,       L + r * 32 + ko);
    stage16(G + (size_t)(row0 + 64 + r) * NPAD + k0 + ko,  L + (64 + r) * 32 + ko);
}

template <bool IS_GEMM2>
__global__ __launch_bounds__(256) void gemm_mfma(const _Float16* __restrict__ A,
                                                 const _Float16* __restrict__ Bt,
                                                 float* __restrict__ C) {
    __shared__ __align__(16) _Float16 As[128 * 32];
    __shared__ __align__(16) _Float16 Bs[128 * 32];

    int tid  = threadIdx.x;
    int lane = tid & 63, wave = tid >> 6;
    int quad = lane >> 4, l16 = lane & 15;
    int rowOff = (wave >> 1) * 64, colOff = (wave & 1) * 64;
    int rowBase = blockIdx.y * 128, colBase = blockIdx.x * 128;

    f32x4 acc[4][4] = {};

    for (int k0 = 0; k0 < NPAD; k0 += 32) {
        stage_tile(A,  rowBase, k0, As, tid);
        stage_tile(Bt, colBase, k0, Bs, tid);
        __syncthreads();

        half8 af[4], bf[4];
#pragma unroll
        for (int i = 0; i < 4; ++i)
            af[i] = *(const half8*)&As[(rowOff + i * 16 + l16) * 32 + quad * 8];
#pragma unroll
        for (int j = 0; j < 4; ++j)
            bf[j] = *(const half8*)&Bs[(colOff + j * 16 + l16) * 32 + quad * 8];
#pragma unroll
        for (int i = 0; i < 4; ++i)
#pragma unroll
            for (int j = 0; j < 4; ++j)
                acc[i][j] = __builtin_amdgcn_mfma_f32_16x16x32_f16(af[i], bf[j], acc[i][j], 0, 0, 0);
        __syncthreads();
    }

    // C/D layout: col = l16, row = quad*4 + reg
#pragma unroll
    for (int i = 0; i < 4; ++i) {
#pragma unroll
        for (int j = 0; j < 4; ++j) {
            int col = colBase + colOff + j * 16 + l16;
#pragma unroll
            for (int r = 0; r < 4; ++r) {
                int row = rowBase + rowOff + i * 16 + quad * 4 + r;
                if (!IS_GEMM2) {
                    C[(size_t)row * NPAD + col] = acc[i][j][r];
                } else {
                    if (row < ROWS2) {
                        int b = row / T_OUT, t2 = row % T_OUT;
                        int k = col >> 1, c = col & 1;
                        C[(((size_t)b * 512 + k) * T_OUT + t2) * 2 + c] = acc[i][j][r];
                    }
                }
            }
        }
    }
}

// ------------------------------- OLA + gather ------------------------------

__global__ void ola(const float* __restrict__ frames, float* __restrict__ sig) {
    int s = blockIdx.x * 256 + threadIdx.x;
    int b = blockIdx.y;
    if (s >= L_OLA) return;
    int tmin = (s - (WIN - 1) + (HOP - 1)) / HOP;
    if (tmin < 0) tmin = 0;
    int tmax = s >> 8;
    if (tmax > T_IN - 1) tmax = T_IN - 1;
    float acc = 0.f;
    for (int t = tmin; t <= tmax; ++t)
        acc += frames[(size_t)(b * T_IN + t) * NPAD + (s - t * HOP)];
    sig[(size_t)b * L_OLA + s] = acc;
}

// fr[row=b*62+t2][j] = sig[b][keep(t2*256+j)] fp16; zero outside valid range
__global__ void pack_fr(const float* __restrict__ sig, _Float16* __restrict__ fr) {
    int row = blockIdx.x;
    _Float16* dst = fr + (size_t)row * NPAD;
    if (row >= ROWS2) {
        for (int j = threadIdx.x; j < NPAD; j += 256) dst[j] = (_Float16)0.f;
        return;
    }
    int b = row / T_OUT, t2 = row % T_OUT;
    for (int j = threadIdx.x; j < NPAD; j += 256) {
        float v = 0.f;
        if (j < WIN) {
            int i = t2 * HOP + j;
            int s = (i < HALF_KEPT) ? (2 * i) : (i + HALF_KEPT);
            v = sig[(size_t)b * L_OLA + s];
        }
        dst[j] = (_Float16)v;
    }
}

// ------------------------------- launcher ----------------------------------

extern "C" void kernel_launch(void* const* d_in, const int* in_sizes, int n_in,
                              void* d_out, int out_size, void* d_ws, size_t ws_size,
                              hipStream_t stream) {
    const float* in = (const float*)d_in[0];
    float* out = (float*)d_out;
    char* ws = (char*)d_ws;

    _Float16* M1T    = (_Float16*)ws;                                   // 2 MB
    _Float16* M2T    = M1T + (size_t)NPAD * NPAD;                       // 2 MB
    _Float16* A1     = M2T + (size_t)NPAD * NPAD;                       // 16 MB
    _Float16* fr     = A1 + (size_t)ROWS1P * NPAD;                      // 8 MB
    float*    frames = (float*)(fr + (size_t)ROWS2P * NPAD);            // 32 MB
    float*    sig    = frames + (size_t)ROWS1P * NPAD;                  // 8.5 MB
    float*    synth  = sig + (size_t)NB * L_OLA;
    float*    window = synth + NPAD;

    build_windows<<<4, 256, 0, stream>>>(synth, window);
    build_m1t<<<(NPAD * NPAD) / 256, 256, 0, stream>>>(M1T, synth);
    build_m2t<<<(NPAD * NPAD) / 256, 256, 0, stream>>>(M2T, window);
    pack_a<<<ROWS1P, 256, 0, stream>>>(in, A1);
    gemm_mfma<false><<<dim3(NPAD / 128, ROWS1P / 128), 256, 0, stream>>>(A1, M1T, frames);
    ola<<<dim3((L_OLA + 255) / 256, NB), 256, 0, stream>>>(frames, sig);
    pack_fr<<<ROWS2P, 256, 0, stream>>>(sig, fr);
    gemm_mfma<true><<<dim3(NPAD / 128, ROWS2P / 128), 256, 0, stream>>>(fr, M2T, out);
}

// Round 3
// 161.359 us; speedup vs baseline: 3.3721x; 1.2094x over previous
//
#include <hip/hip_runtime.h>

// ---------------------------------------------------------------------------
// Downsampling — fp16 MFMA, fast builders, fused OLA+decimate+frame.
//   build:  M1T/M2T fp16 DFT tables via __sincosf (HW sin/cos)
//   pack_a: LDS-tiled transpose  in[b,k,t,c] -> A1[b*127+t][2k+c] fp16
//   gemm1:  frames[8192,1024]f16 = A1 @ M1T^T            (MFMA 16x16x32)
//   ola_pack: fr[4096,1024]f16 = frame(decimate(OLA(frames))) (fused, no sig)
//   gemm2:  out = fr @ M2T^T, scatter into (b,512,62,2)   (MFMA 16x16x32)
// ---------------------------------------------------------------------------

#define WIN       1022
#define HOP       256
#define T_IN      127
#define NB        64
#define NPAD      1024
#define L_OLA     33278     // (127-1)*256 + 1022
#define L_OUT     16670     // 16608 kept even + 62 tail
#define T_OUT     62
#define HALF_KEPT 16608     // 33216/2
#define ROWS1     (NB * T_IN)    // 8128
#define ROWS1P    8192
#define ROWS2     (NB * T_OUT)   // 3968
#define ROWS2P    4096
#define TWO_PI_F  6.28318530717958647692f

typedef _Float16 half8 __attribute__((ext_vector_type(8)));
typedef float    f32x4 __attribute__((ext_vector_type(4)));

// ------------------------------- table builders ----------------------------

__global__ void build_windows(float* __restrict__ synth, float* __restrict__ window) {
    int j = blockIdx.x * blockDim.x + threadIdx.x;
    if (j >= NPAD) return;
    if (j >= WIN) { synth[j] = 0.f; window[j] = 0.f; return; }
    const float c = TWO_PI_F / (float)WIN;
    float w = 0.5f - 0.5f * cosf(c * (float)j);
    int p = j & (HOP - 1);
    float dd = 0.f;
    for (int r = 0; r < 4; ++r) {
        int idx = p + HOP * r;
        if (idx < WIN) {
            float wi = 0.5f - 0.5f * cosf(c * (float)idx);
            dd += wi * wi;
        }
    }
    synth[j]  = w / dd;
    window[j] = w;
}

// M1T[j][kk] = irfft basis * synth, kk = 2k+c.  (transposed vs math layout)
__global__ void build_m1t(_Float16* __restrict__ M1T, const float* __restrict__ synth) {
    int idx = blockIdx.x * blockDim.x + threadIdx.x;   // 1024*1024
    int j = idx >> 10, kk = idx & 1023;
    float v = 0.f;
    if (j < WIN) {
        int k = kk >> 1, c = kk & 1;
        if (!(c == 1 && (k == 0 || k == 511))) {       // Im of DC/Nyquist ignored
            float a = (k == 0 || k == 511) ? (1.f / (float)WIN) : (2.f / (float)WIN);
            int m = (k * j) % WIN;                     // exact phase reduction
            float ang = (float)m * (TWO_PI_F / (float)WIN);
            float s, co;
            __sincosf(ang, &s, &co);
            v = a * synth[j] * (c == 0 ? co : -s);
        }
    }
    M1T[idx] = (_Float16)v;
}

// M2T[col][j] = rfft basis * hann, col = 2k+c.  (transposed: row=output col)
__global__ void build_m2t(_Float16* __restrict__ M2T, const float* __restrict__ window) {
    int idx = blockIdx.x * blockDim.x + threadIdx.x;   // 1024*1024
    int col = idx >> 10, j = idx & 1023;
    float v = 0.f;
    if (j < WIN) {
        int k = col >> 1, c = col & 1;
        int m = (k * j) % WIN;
        float ang = (float)m * (TWO_PI_F / (float)WIN);
        float s, co;
        __sincosf(ang, &s, &co);
        v = window[j] * (c == 0 ? co : -s);
    }
    M2T[idx] = (_Float16)v;
}

// ------------------------------- pack A (LDS transpose) --------------------
// Block (kt, b): k0 = kt*32; reads 32*254 contiguous floats, writes 127 rows
// of 64 contiguous fp16. b==64 zero-fills the pad rows 8128..8191.
__global__ __launch_bounds__(256) void pack_a(const float* __restrict__ in,
                                              _Float16* __restrict__ A1) {
    __shared__ float lds[32 * 254];
    int tid = threadIdx.x;
    int k0 = blockIdx.x * 32;
    int b  = blockIdx.y;
    if (b == NB) {  // pad rows
        for (int f = tid; f < 64 * 64; f += 256) {
            int r = f >> 6, cc = f & 63;
            A1[(size_t)(ROWS1 + r) * NPAD + 2 * k0 + cc] = (_Float16)0.f;
        }
        return;
    }
    const float* base = in + ((size_t)b * 512 + k0) * (T_IN * 2);
    for (int idx = tid; idx < 32 * 254; idx += 256)
        lds[idx] = base[idx];
    __syncthreads();
    // f = t*64 + l ; l = 2*(k-k0)+c
    for (int f = tid; f < T_IN * 64; f += 256) {
        int t = f >> 6, l = f & 63;
        int dk = l >> 1, c = l & 1;
        A1[(size_t)(b * T_IN + t) * NPAD + 2 * k0 + l] =
            (_Float16)lds[dk * 254 + t * 2 + c];
    }
}

// ------------------------------- MFMA GEMM ---------------------------------
// C[128x128] per block; 4 waves in 2x2; per wave 4x4 tiles of 16x16.

__device__ __forceinline__ void stage16(const void* g, void* l) {
    __builtin_amdgcn_global_load_lds(
        (const __attribute__((address_space(1))) unsigned int*)g,
        (__attribute__((address_space(3))) unsigned int*)l, 16, 0, 0);
}

__device__ __forceinline__ void stage_tile(const _Float16* __restrict__ G,
                                           int row0, int k0,
                                           _Float16* __restrict__ L, int tid) {
    int r = tid >> 2, ko = (tid & 3) * 8;
    stage16(G + (size_t)(row0 + r) * NPAD + k0 + ko,       L + r * 32 + ko);
    stage16(G + (size_t)(row0 + 64 + r) * NPAD + k0 + ko,  L + (64 + r) * 32 + ko);
}

template <bool IS_GEMM2>
__global__ __launch_bounds__(256) void gemm_mfma(const _Float16* __restrict__ A,
                                                 const _Float16* __restrict__ Bt,
                                                 void* __restrict__ Cv) {
    __shared__ __align__(16) _Float16 As[128 * 32];
    __shared__ __align__(16) _Float16 Bs[128 * 32];

    int tid  = threadIdx.x;
    int lane = tid & 63, wave = tid >> 6;
    int quad = lane >> 4, l16 = lane & 15;
    int rowOff = (wave >> 1) * 64, colOff = (wave & 1) * 64;
    int rowBase = blockIdx.y * 128, colBase = blockIdx.x * 128;

    f32x4 acc[4][4] = {};

    for (int k0 = 0; k0 < NPAD; k0 += 32) {
        stage_tile(A,  rowBase, k0, As, tid);
        stage_tile(Bt, colBase, k0, Bs, tid);
        __syncthreads();

        half8 af[4], bf[4];
#pragma unroll
        for (int i = 0; i < 4; ++i)
            af[i] = *(const half8*)&As[(rowOff + i * 16 + l16) * 32 + quad * 8];
#pragma unroll
        for (int j = 0; j < 4; ++j)
            bf[j] = *(const half8*)&Bs[(colOff + j * 16 + l16) * 32 + quad * 8];
#pragma unroll
        for (int i = 0; i < 4; ++i)
#pragma unroll
            for (int j = 0; j < 4; ++j)
                acc[i][j] = __builtin_amdgcn_mfma_f32_16x16x32_f16(af[i], bf[j], acc[i][j], 0, 0, 0);
        __syncthreads();
    }

    // C/D layout: col = l16, row = quad*4 + reg
#pragma unroll
    for (int i = 0; i < 4; ++i) {
#pragma unroll
        for (int j = 0; j < 4; ++j) {
            int col = colBase + colOff + j * 16 + l16;
#pragma unroll
            for (int r = 0; r < 4; ++r) {
                int row = rowBase + rowOff + i * 16 + quad * 4 + r;
                if (!IS_GEMM2) {
                    ((_Float16*)Cv)[(size_t)row * NPAD + col] = (_Float16)acc[i][j][r];
                } else if (row < ROWS2) {
                    int b = row / T_OUT, t2 = row % T_OUT;
                    int k = col >> 1, c = col & 1;
                    ((float*)Cv)[(((size_t)b * 512 + k) * T_OUT + t2) * 2 + c] = acc[i][j][r];
                }
            }
        }
    }
}

// ------------------------- fused OLA + decimate + frame --------------------
// For each kept sample i: s = keep(i); v = OLA(frames)[s]; scatter v into all
// stage-2 frame positions (t2, j=i-256*t2).  fr pad (j>=1022, rows>=3968) is
// zeroed by the memsetAsync in kernel_launch.
__global__ void ola_pack(const _Float16* __restrict__ frames,
                         _Float16* __restrict__ fr) {
    int i = blockIdx.x * 256 + threadIdx.x;
    int b = blockIdx.y;
    if (i >= L_OUT) return;
    int s = (i < HALF_KEPT) ? (2 * i) : (i + HALF_KEPT);

    int tmin = (s > WIN - 1) ? ((s - (WIN - 1) + HOP - 1) >> 8) : 0;
    int tmax = s >> 8; if (tmax > T_IN - 1) tmax = T_IN - 1;
    float v = 0.f;
    for (int t = tmin; t <= tmax; ++t)
        v += (float)frames[(size_t)(b * T_IN + t) * NPAD + (s - t * HOP)];

    _Float16 hv = (_Float16)v;
    int t2min = (i > WIN - HOP - 1) ? ((i - (WIN - 1) + HOP - 1) >> 8) : 0;
    int t2max = i >> 8; if (t2max > T_OUT - 1) t2max = T_OUT - 1;
    for (int t2 = t2min; t2 <= t2max; ++t2)
        fr[(size_t)(b * T_OUT + t2) * NPAD + (i - t2 * HOP)] = hv;
}

// ------------------------------- launcher ----------------------------------

extern "C" void kernel_launch(void* const* d_in, const int* in_sizes, int n_in,
                              void* d_out, int out_size, void* d_ws, size_t ws_size,
                              hipStream_t stream) {
    const float* in = (const float*)d_in[0];
    float* out = (float*)d_out;
    char* ws = (char*)d_ws;

    _Float16* M1T    = (_Float16*)ws;                                   // 2 MB
    _Float16* M2T    = M1T + (size_t)NPAD * NPAD;                       // 2 MB
    _Float16* A1     = M2T + (size_t)NPAD * NPAD;                       // 16 MB
    _Float16* fr     = A1 + (size_t)ROWS1P * NPAD;                      // 8 MB
    _Float16* frames = fr + (size_t)ROWS2P * NPAD;                      // 16 MB
    float*    synth  = (float*)(frames + (size_t)ROWS1P * NPAD);
    float*    window = synth + NPAD;

    build_windows<<<4, 256, 0, stream>>>(synth, window);
    build_m1t<<<(NPAD * NPAD) / 256, 256, 0, stream>>>(M1T, synth);
    build_m2t<<<(NPAD * NPAD) / 256, 256, 0, stream>>>(M2T, window);
    pack_a<<<dim3(16, NB + 1), 256, 0, stream>>>(in, A1);
    gemm_mfma<false><<<dim3(NPAD / 128, ROWS1P / 128), 256, 0, stream>>>(A1, M1T, frames);
    hipMemsetAsync(fr, 0, (size_t)ROWS2P * NPAD * sizeof(_Float16), stream);
    ola_pack<<<dim3((L_OUT + 255) / 256, NB), 256, 0, stream>>>(frames, fr);
    gemm_mfma<true><<<dim3(NPAD / 128, ROWS2P / 128), 256, 0, stream>>>(fr, M2T, out);
}

// Round 4
// 156.477 us; speedup vs baseline: 3.4773x; 1.0312x over previous
//
#include <hip/hip_runtime.h>

// ---------------------------------------------------------------------------
// Downsampling — fp16 MFMA, even-column-compacted stage 1, 4 kernels total.
//   prep:   M1T[1024][1024] (even rows + odd rows>=961), M2T, A1 (transpose)
//   gemm1:  fe[8192][512] = A1 @ (even rows of M1T)^T   — only even samples
//           of the OLA signal are ever kept (decimation by 2); tail handled
//           separately (only t=126 reaches s>=33216).
//   ola_pack: fr[4096][1024]f16 = frame(decimate(OLA)) ; odd-tail samples
//           (15/batch) computed as direct 1024-dots A1row(126)·M1T[p].
//   gemm2:  out = fr @ M2T^T, scatter into (b,512,62,2)
// No zero-fill passes: fr/A1 pad rows only affect discarded C rows; fr pad
// cols hit zero rows of M2T; 0xAA fp16 poison is a small normal (no NaN).
// ---------------------------------------------------------------------------

#define WIN       1022
#define HOP       256
#define T_IN      127
#define NB        64
#define NPAD      1024
#define NE        512       // even-compacted stage-1 columns
#define T_OUT     62
#define HALF_KEPT 16608     // 33216/2
#define L_USE     16638     // kept samples beyond 16637 feed no output frame
#define ROWS1     8128
#define ROWS1P    8192
#define ROWS2     3968
#define ROWS2P    4096
#define TWO_PI_F  6.28318530717958647692f

typedef _Float16 half8 __attribute__((ext_vector_type(8)));
typedef float    f32x4 __attribute__((ext_vector_type(4)));

// ------------------------------- fused prep --------------------------------
// blocks [0,4096):    M1T  (skips odd rows < 961 — never read)
// blocks [4096,8192): M2T
// blocks [8192,9216): pack_a LDS transpose in[b,k,t,c] -> A1[b*127+t][2k+c]
__global__ __launch_bounds__(256) void prep(const float* __restrict__ in,
                                            _Float16* __restrict__ M1T,
                                            _Float16* __restrict__ M2T,
                                            _Float16* __restrict__ A1) {
    __shared__ float lds[32 * 254];
    int bx = blockIdx.x, tid = threadIdx.x;
    const float cc = TWO_PI_F / (float)WIN;

    if (bx < 4096) {                       // ---- M1T[j][kk], irfft*synth
        int idx = bx * 256 + tid, j = idx >> 10, kk = idx & 1023;
        if ((j & 1) && j < 961) return;    // odd rows <961 never read
        float v = 0.f;
        if (j < WIN) {
            float w = 0.5f - 0.5f * __cosf(cc * (float)j);
            float dd = 0.f;
            int p = j & (HOP - 1);
            for (int r = 0; r < 4; ++r) {
                int ix = p + HOP * r;
                if (ix < WIN) {
                    float wi = 0.5f - 0.5f * __cosf(cc * (float)ix);
                    dd += wi * wi;
                }
            }
            float synth = w / dd;
            int k = kk >> 1, c = kk & 1;
            if (!(c == 1 && (k == 0 || k == 511))) {   // Im of DC/Nyquist ignored
                float a = (k == 0 || k == 511) ? (1.f / (float)WIN) : (2.f / (float)WIN);
                int m = (k * j) % WIN;                 // exact phase reduction
                float s, co;
                __sincosf((float)m * cc, &s, &co);
                v = a * synth * (c == 0 ? co : -s);
            }
        }
        M1T[idx] = (_Float16)v;
        return;
    }
    if (bx < 8192) {                       // ---- M2T[col][j], rfft*hann
        int idx = (bx - 4096) * 256 + tid, col = idx >> 10, j = idx & 1023;
        float v = 0.f;
        if (j < WIN) {
            float w = 0.5f - 0.5f * __cosf(cc * (float)j);
            int k = col >> 1, c = col & 1;
            int m = (k * j) % WIN;
            float s, co;
            __sincosf((float)m * cc, &s, &co);
            v = w * (c == 0 ? co : -s);
        }
        M2T[idx] = (_Float16)v;
        return;
    }
    // ---- pack_a: 1024 blocks (16 k-tiles x 64 batches)
    int bx2 = bx - 8192;
    int kt = bx2 >> 6, b = bx2 & 63;
    const float* base = in + ((size_t)b * 512 + kt * 32) * (T_IN * 2);
    for (int idx2 = tid; idx2 < 32 * 254; idx2 += 256)
        lds[idx2] = base[idx2];
    __syncthreads();
    for (int f = tid; f < T_IN * 64; f += 256) {
        int t = f >> 6, l = f & 63;
        int dk = l >> 1, c = l & 1;
        A1[(size_t)(b * T_IN + t) * NPAD + kt * 64 + l] =
            (_Float16)lds[dk * 254 + t * 2 + c];
    }
}

// ------------------------------- MFMA GEMM ---------------------------------
// 128x64 C-tile per block, 4 waves (2 row-halves x 2 col-halves),
// per wave 4x2 tiles of 16x16. BPITCH=2048 makes B read even rows of M1T.

__device__ __forceinline__ void stage16(const void* g, void* l) {
    __builtin_amdgcn_global_load_lds(
        (const __attribute__((address_space(1))) unsigned int*)g,
        (__attribute__((address_space(3))) unsigned int*)l, 16, 0, 0);
}

template <bool G2, int BPITCH, int CPITCH>
__global__ __launch_bounds__(256) void gemm_mfma(const _Float16* __restrict__ A,
                                                 const _Float16* __restrict__ B0,
                                                 void* __restrict__ Cv) {
    __shared__ __align__(16) _Float16 As[128 * 32];
    __shared__ __align__(16) _Float16 Bs[64 * 32];

    int tid  = threadIdx.x;
    int lane = tid & 63, wave = tid >> 6;
    int quad = lane >> 4, l16 = lane & 15;
    int rowOff = (wave >> 1) * 64, colOff = (wave & 1) * 32;
    int rowBase = blockIdx.y * 128, colBase = blockIdx.x * 64;

    int r = tid >> 2, ko = (tid & 3) * 8;
    const _Float16* Arow0 = A + (size_t)(rowBase + r) * NPAD + ko;
    const _Float16* Arow1 = Arow0 + (size_t)64 * NPAD;
    const _Float16* Brow  = B0 + (size_t)(colBase + r) * BPITCH + ko;

    f32x4 acc[4][2] = {};

    for (int k0 = 0; k0 < NPAD; k0 += 32) {
        stage16(Arow0 + k0, As + r * 32 + ko);
        stage16(Arow1 + k0, As + (64 + r) * 32 + ko);
        stage16(Brow  + k0, Bs + r * 32 + ko);
        __syncthreads();

        half8 af[4], bf[2];
#pragma unroll
        for (int i = 0; i < 4; ++i)
            af[i] = *(const half8*)&As[(rowOff + i * 16 + l16) * 32 + quad * 8];
#pragma unroll
        for (int j = 0; j < 2; ++j)
            bf[j] = *(const half8*)&Bs[(colOff + j * 16 + l16) * 32 + quad * 8];
#pragma unroll
        for (int i = 0; i < 4; ++i)
#pragma unroll
            for (int j = 0; j < 2; ++j)
                acc[i][j] = __builtin_amdgcn_mfma_f32_16x16x32_f16(af[i], bf[j], acc[i][j], 0, 0, 0);
        __syncthreads();
    }

    // C/D layout: col = l16, row = quad*4 + reg
#pragma unroll
    for (int i = 0; i < 4; ++i) {
#pragma unroll
        for (int j = 0; j < 2; ++j) {
            int col = colBase + colOff + j * 16 + l16;
#pragma unroll
            for (int rr = 0; rr < 4; ++rr) {
                int row = rowBase + rowOff + i * 16 + quad * 4 + rr;
                if (!G2) {
                    ((_Float16*)Cv)[(size_t)row * CPITCH + col] = (_Float16)acc[i][j][rr];
                } else if (row < ROWS2) {
                    int b = row / T_OUT, t2 = row % T_OUT;
                    int k = col >> 1, c = col & 1;
                    ((float*)Cv)[(((size_t)b * 512 + k) * T_OUT + t2) * 2 + c] = acc[i][j][rr];
                }
            }
        }
    }
}

// ------------------------- fused OLA + decimate + frame --------------------
__global__ void ola_pack(const _Float16* __restrict__ fe,
                         const _Float16* __restrict__ A1,
                         const _Float16* __restrict__ M1T,
                         _Float16* __restrict__ fr) {
    int i = blockIdx.x * 256 + threadIdx.x;
    int b = blockIdx.y;
    if (i >= L_USE) return;

    float v = 0.f;
    if (i < HALF_KEPT) {                   // s = 2i even: compacted OLA
        int tmin = (i > 510) ? ((i - 383) >> 7) : 0;
        int tmax = i >> 7; if (tmax > T_IN - 1) tmax = T_IN - 1;
        for (int t = tmin; t <= tmax; ++t)
            v += (float)fe[(size_t)(b * T_IN + t) * NE + (i - t * 128)];
    } else {                               // tail: only t=126 contributes
        int s = i + HALF_KEPT;             // 33216..33245
        int p = s - 32256;                 // 960..989
        if (!(s & 1)) {
            v = (float)fe[(size_t)(b * T_IN + 126) * NE + (p >> 1)];
        } else {                           // odd p: direct 1024-dot
            const _Float16* ar = A1 + (size_t)(b * T_IN + 126) * NPAD;
            const _Float16* mr = M1T + (size_t)p * NPAD;
            float a0 = 0.f;
            for (int k = 0; k < NPAD; k += 8) {
                half8 av = *(const half8*)&ar[k];
                half8 mv = *(const half8*)&mr[k];
#pragma unroll
                for (int u = 0; u < 8; ++u)
                    a0 += (float)av[u] * (float)mv[u];
            }
            v = a0;
        }
    }

    _Float16 hv = (_Float16)v;
    int t2min = (i > WIN - 1) ? ((i - (WIN - 1) + HOP - 1) >> 8) : 0;
    int t2max = i >> 8; if (t2max > T_OUT - 1) t2max = T_OUT - 1;
    for (int t2 = t2min; t2 <= t2max; ++t2)
        fr[(size_t)(b * T_OUT + t2) * NPAD + (i - t2 * HOP)] = hv;
}

// ------------------------------- launcher ----------------------------------

extern "C" void kernel_launch(void* const* d_in, const int* in_sizes, int n_in,
                              void* d_out, int out_size, void* d_ws, size_t ws_size,
                              hipStream_t stream) {
    const float* in = (const float*)d_in[0];
    float* out = (float*)d_out;
    char* ws = (char*)d_ws;

    _Float16* M1T = (_Float16*)ws;                        // 2 MB
    _Float16* M2T = M1T + (size_t)NPAD * NPAD;            // 2 MB
    _Float16* A1  = M2T + (size_t)NPAD * NPAD;            // 16 MB
    _Float16* fr  = A1 + (size_t)ROWS1P * NPAD;           // 8 MB
    _Float16* fe  = fr + (size_t)ROWS2P * NPAD;           // 8 MB

    prep<<<9216, 256, 0, stream>>>(in, M1T, M2T, A1);
    gemm_mfma<false, 2 * NPAD, NE><<<dim3(NE / 64, ROWS1P / 128), 256, 0, stream>>>(A1, M1T, fe);
    ola_pack<<<dim3(65, NB), 256, 0, stream>>>(fe, A1, M1T, fr);
    gemm_mfma<true, NPAD, 0><<<dim3(NPAD / 64, ROWS2P / 128), 256, 0, stream>>>(fr, M2T, out);
}